// Round 6
// baseline (302.440 us; speedup 1.0000x reference)
//
#include <hip/hip_runtime.h>
#include <hip/hip_bf16.h>

#define IN_CH 4096
#define OUT_CH 11008
#define QBLK 64

#define BM 128
#define BN 64
#define BK 64
#define KCHUNKS (IN_CH / BK)            // 64
#define KSPLIT 4
#define SPLIT_CHUNKS (KCHUNKS / KSPLIT) // 16
#define NTILES (OUT_CH / BN)            // 172
#define XCONV_BLOCKS 16
#define BPAD 72                          // B LDS row stride (64 + 8 pad)

typedef short bf16x8 __attribute__((ext_vector_type(8)));
typedef float f32x4 __attribute__((ext_vector_type(4)));

#define GLOBAL_AS __attribute__((address_space(1)))
#define LDS_AS __attribute__((address_space(3)))

__device__ inline unsigned short f2bf(float f) {
    union { __hip_bfloat16 h; unsigned short u; } cv;
    cv.h = __float2bfloat16(f);
    return cv.u;
}

// dequant 4 fp32 -> 4 bf16 with exact LPBQ math (bit-identical to reference:
// true fp32 div, rintf = round-half-even, clip, multiply back, bf16 round)
__device__ inline void dq4(float4 v, float s1, short* o) {
    o[0] = (short)f2bf(fminf(fmaxf(rintf(v.x / s1), -8.0f), 7.0f) * s1);
    o[1] = (short)f2bf(fminf(fmaxf(rintf(v.y / s1), -8.0f), 7.0f) * s1);
    o[2] = (short)f2bf(fminf(fmaxf(rintf(v.z / s1), -8.0f), 7.0f) * s1);
    o[3] = (short)f2bf(fminf(fmaxf(rintf(v.w / s1), -8.0f), 7.0f) * s1);
}

// ---------------------------------------------------------------------------
// Kernel 1 (scale-only): per-row s1r -> s1rT[kblock][row]. No wq write — the
// GEMM re-derives w_q from the (L3-resident) fp32 weight directly.
// Blocks [OUT_CH, OUT_CH+16) convert x -> bf16, XOR-swizzled granules:
//   xq[row][kc*64 + g*8 + t] = bf16(x[row][kc*64 + (g^(row&7))*8 + t])
// so global_load_lds's rigid lane->LDS mapping yields conflict-free MFMA
// fragment reads in the GEMM.
// ---------------------------------------------------------------------------
__global__ __launch_bounds__(256) void scale_kernel(
        const float* __restrict__ w, const float* __restrict__ x,
        float* __restrict__ s1rT, unsigned short* __restrict__ xq) {
    const int tid = threadIdx.x;

    if (blockIdx.x >= OUT_CH) {
        // ---- x fp32 -> bf16, swizzled. 65536 granules of 8 el. ----
        const int bx = blockIdx.x - OUT_CH;
        for (int it = 0; it < 16; ++it) {
            const int G = it * 4096 + bx * 256 + tid;   // granule id
            const int row = G >> 9;                     // 512 granules/row
            const int gi = G & 511;                     // granule in row
            const int kc = gi >> 3;
            const int gp = gi & 7;
            const int gl = gp ^ (row & 7);              // logical granule
            const float4* src =
                (const float4*)(x + (size_t)row * IN_CH + kc * 64 + gl * 8);
            float4 a = src[0], b = src[1];
            ushort4 o0, o1;
            o0.x = f2bf(a.x); o0.y = f2bf(a.y); o0.z = f2bf(a.z); o0.w = f2bf(a.w);
            o1.x = f2bf(b.x); o1.y = f2bf(b.y); o1.z = f2bf(b.z); o1.w = f2bf(b.w);
            ushort4* dst = (ushort4*)(xq + (size_t)row * IN_CH + gi * 8);
            dst[0] = o0;
            dst[1] = o1;
        }
        return;
    }

    const int row = blockIdx.x;
    const float* wrow = w + (size_t)row * IN_CH;

    __shared__ float s1_lds[64];
    const int lane16 = tid & 15;

    // Pass A: per-64-block max|.| -> s1 (16 lanes per quant-block)
    for (int p = 0; p < 4; ++p) {
        float4 v = ((const float4*)wrow)[p * 256 + tid];
        float m = fmaxf(fmaxf(fabsf(v.x), fabsf(v.y)),
                        fmaxf(fabsf(v.z), fabsf(v.w)));
        m = fmaxf(m, __shfl_xor(m, 1));
        m = fmaxf(m, __shfl_xor(m, 2));
        m = fmaxf(m, __shfl_xor(m, 4));
        m = fmaxf(m, __shfl_xor(m, 8));
        if (lane16 == 0)
            s1_lds[p * 16 + (tid >> 4)] = fmaxf(m * (1.0f / 7.0f), 1e-8f);
    }
    __syncthreads();

    // Pass B: s2 = clip(max_b s1 / 15, 1e-8); s1r = clip(rint(s1/s2),0,15)*s2
    if (tid < 64) {
        float s1 = s1_lds[tid];
        float m = s1;
        m = fmaxf(m, __shfl_xor(m, 1));
        m = fmaxf(m, __shfl_xor(m, 2));
        m = fmaxf(m, __shfl_xor(m, 4));
        m = fmaxf(m, __shfl_xor(m, 8));
        m = fmaxf(m, __shfl_xor(m, 16));
        m = fmaxf(m, __shfl_xor(m, 32));
        const float s2 = fmaxf(m * (1.0f / 15.0f), 1e-8f);
        const float s1q = fminf(fmaxf(rintf(s1 / s2), 0.0f), 15.0f);
        s1rT[(size_t)tid * OUT_CH + row] = s1q * s2;   // transposed store
    }
}

// ---------------------------------------------------------------------------
// Kernel 2: K-split GEMM; B tile dequantized on the fly from fp32 W (L3-hot
// after kernel 1's streaming pass — R4 measured this re-read as 100% L3 hit).
// A staged via global_load_lds w=16 from swizzled xq; fragment reads
// un-swizzle with pg = (kk*4+quad)^(row&7) -> conflict-free.
// W regs for chunk kc+1 prefetched after barrier 1 (latency rides MFMA).
// ---------------------------------------------------------------------------
__global__ __launch_bounds__(256) void gemm_kernel(
        const unsigned short* __restrict__ A, const float* __restrict__ W,
        const float* __restrict__ s1rT, float* __restrict__ part) {
    __shared__ __align__(16) unsigned short ldsA[BM * BK];   // 16 KB
    __shared__ __align__(16) unsigned short ldsB[BN * BPAD]; // 9 KB, padded

    const int tid = threadIdx.x;
    const int w = tid >> 6;
    const int l = tid & 63;
    const int wm = w >> 1;
    const int wn = w & 1;
    const int n0 = blockIdx.x * BN;
    const int kc0 = blockIdx.y * SPLIT_CHUNKS;

    const int r8 = l >> 3;       // A staging: row within 8-row group
    const int sg = l & 7;        // A staging: 16B segment in 128B row

    const int brow = tid >> 2;   // B staging: row 0..63 (4 thr/row)
    const int bcg = tid & 3;     // B staging: 16-el col group

    f32x4 acc[4][2] = {};

    const int lane15 = l & 15;
    const int quad = l >> 4;

    // W source pointer for this thread's 16-element B segment
    const float* wseg = W + (size_t)(n0 + brow) * IN_CH + bcg * 16;

    // prefetch chunk kc0's 16 fp32
    float4 c0 = ((const float4*)(wseg + kc0 * 64))[0];
    float4 c1 = ((const float4*)(wseg + kc0 * 64))[1];
    float4 c2 = ((const float4*)(wseg + kc0 * 64))[2];
    float4 c3 = ((const float4*)(wseg + kc0 * 64))[3];

    for (int kc = kc0; kc < kc0 + SPLIT_CHUNKS; ++kc) {
        const int k0 = kc * BK;

        // ---- A tile: async global -> LDS (swizzled content) ----
        for (int i = 0; i < 4; ++i) {
            const unsigned short* gp =
                A + (size_t)(i * 32 + w * 8 + r8) * IN_CH + k0 + sg * 8;
            LDS_AS unsigned short* lp =
                (LDS_AS unsigned short*)&ldsA[(i * 32 + w * 8) * BK];
            __builtin_amdgcn_global_load_lds((const GLOBAL_AS void*)gp,
                                             (LDS_AS void*)lp, 16, 0, 0);
        }

        // ---- B tile: dequant prefetched fp32 -> LDS bf16 (padded rows) ----
        const float s1 = s1rT[(size_t)kc * OUT_CH + n0 + brow];
        {
            bf16x8 ob0, ob1;
            short t0[4], t1[4], t2[4], t3[4];
            dq4(c0, s1, t0); dq4(c1, s1, t1); dq4(c2, s1, t2); dq4(c3, s1, t3);
            ob0[0] = t0[0]; ob0[1] = t0[1]; ob0[2] = t0[2]; ob0[3] = t0[3];
            ob0[4] = t1[0]; ob0[5] = t1[1]; ob0[6] = t1[2]; ob0[7] = t1[3];
            ob1[0] = t2[0]; ob1[1] = t2[1]; ob1[2] = t2[2]; ob1[3] = t2[3];
            ob1[4] = t3[0]; ob1[5] = t3[1]; ob1[6] = t3[2]; ob1[7] = t3[3];
            *(bf16x8*)&ldsB[brow * BPAD + bcg * 16] = ob0;
            *(bf16x8*)&ldsB[brow * BPAD + bcg * 16 + 8] = ob1;
        }

        asm volatile("s_waitcnt vmcnt(0)" ::: "memory");
        __syncthreads();   // barrier 1

        // ---- W prefetch for kc+1: L3 latency overlaps MFMA ----
        if (kc + 1 < kc0 + SPLIT_CHUNKS) {
            const float* np = wseg + (kc + 1) * 64;
            c0 = ((const float4*)np)[0];
            c1 = ((const float4*)np)[1];
            c2 = ((const float4*)np)[2];
            c3 = ((const float4*)np)[3];
        }

        // ---- MFMA over the 64-deep chunk ----
        for (int kk = 0; kk < 2; ++kk) {
            bf16x8 af[4], bfv[2];
            const int ko = kk * 32 + quad * 8;          // logical k offset
            for (int i = 0; i < 4; ++i) {
                const int row = wm * 64 + i * 16 + lane15;
                const int pg = ((kk * 4 + quad) ^ (row & 7)) * 8;  // physical
                af[i] = *(const bf16x8*)&ldsA[row * BK + pg];
            }
            for (int j = 0; j < 2; ++j)
                bfv[j] = *(const bf16x8*)&ldsB[(wn * 32 + j * 16 + lane15) * BPAD + ko];
            for (int i = 0; i < 4; ++i)
                for (int j = 0; j < 2; ++j)
                    acc[i][j] = __builtin_amdgcn_mfma_f32_16x16x32_bf16(
                        af[i], bfv[j], acc[i][j], 0, 0, 0);
        }
        __syncthreads();   // barrier 2
    }

    // ---- epilogue: partial store, C/D layout col=lane&15, row=quad*4+reg ----
    float* pbase = part + (size_t)blockIdx.y * BM * OUT_CH;
    const int m_base = wm * 64 + quad * 4;
    const int n_base = n0 + wn * 32 + lane15;
    for (int j = 0; j < 2; ++j) {
        for (int i = 0; i < 4; ++i) {
            const int m = m_base + i * 16;
            float* cp = pbase + (size_t)m * OUT_CH + n_base + j * 16;
            cp[0 * OUT_CH] = acc[i][j][0];
            cp[1 * OUT_CH] = acc[i][j][1];
            cp[2 * OUT_CH] = acc[i][j][2];
            cp[3 * OUT_CH] = acc[i][j][3];
        }
    }
}

// ---------------------------------------------------------------------------
// Kernel 3: reduce K-split partials + bias. Grid (11, 128) x 256 thr, float4.
// ---------------------------------------------------------------------------
__global__ __launch_bounds__(256) void reduce_kernel(
        const float* __restrict__ part, const float* __restrict__ bias,
        float* __restrict__ out) {
    const int m = blockIdx.y;
    const int x4 = blockIdx.x * 256 + threadIdx.x;
    if (x4 >= OUT_CH / 4) return;
    const size_t off = (size_t)m * OUT_CH + x4 * 4;

    float4 acc = ((const float4*)bias)[x4];
    for (int s = 0; s < KSPLIT; ++s) {
        float4 p = *(const float4*)(part + (size_t)s * BM * OUT_CH + off);
        acc.x += p.x; acc.y += p.y; acc.z += p.z; acc.w += p.w;
    }
    *(float4*)(out + off) = acc;
}

extern "C" void kernel_launch(void* const* d_in, const int* in_sizes, int n_in,
                              void* d_out, int out_size, void* d_ws, size_t ws_size,
                              hipStream_t stream) {
    const float* x = (const float*)d_in[0];       // (1,128,4096) fp32
    const float* weight = (const float*)d_in[1];  // (11008,4096) fp32
    const float* bias = (const float*)d_in[2];    // (11008,) fp32
    float* out = (float*)d_out;                   // (1,128,11008) fp32

    // workspace layout (16B-aligned slices)
    unsigned short* wsX = (unsigned short*)d_ws;                  // 1 MB bf16 x (swizzled)
    float* wsS = (float*)(wsX + (size_t)BM * IN_CH);              // 2.8 MB s1r^T
    float* wsP = wsS + (size_t)QBLK * OUT_CH;                     // 22.5 MB partials

    scale_kernel<<<OUT_CH + XCONV_BLOCKS, 256, 0, stream>>>(weight, x, wsS, wsX);
    gemm_kernel<<<dim3(NTILES, KSPLIT), 256, 0, stream>>>(wsX, weight, wsS, wsP);
    reduce_kernel<<<dim3((OUT_CH / 4 + 255) / 256, BM), 256, 0, stream>>>(
        wsP, bias, out);
}